// Round 12
// baseline (203.076 us; speedup 1.0000x reference)
//
#include <hip/hip_runtime.h>
#include <math.h>

typedef _Float16 half8 __attribute__((ext_vector_type(8)));
typedef __fp16   fp16x2 __attribute__((ext_vector_type(2)));  // cvt_pkrtz's return type
typedef float f32x4 __attribute__((ext_vector_type(4)));

// Branchless exact-grade GELU: x*0.5*(1+erf(x/sqrt(2))) with A&S 7.1.26 erf,
// |erf err| <= 1.5e-7 (vs output threshold 2.47e-2).
__device__ __forceinline__ float gelu_f(float v) {
    float y  = v * 0.70710678118654752f;
    float ay = __builtin_fabsf(y);
    float t  = __builtin_amdgcn_rcpf(__builtin_fmaf(0.3275911f, ay, 1.0f));
    float p  = __builtin_fmaf(t, 1.061405429f, -1.453152027f);
    p = __builtin_fmaf(p, t, 1.421413741f);
    p = __builtin_fmaf(p, t, -0.284496736f);
    p = __builtin_fmaf(p, t, 0.254829592f);
    p = p * t;
    float e  = __builtin_amdgcn_exp2f(ay * ay * -1.4426950408889634f);
    float er = __builtin_fmaf(-p, e, 1.0f);        // erf(|y|), saturates to 1
    er = __builtin_copysignf(er, v);               // restore sign
    float hv = 0.5f * v;
    return __builtin_fmaf(hv, er, hv);
}

#define MFMA16(A, B, C) __builtin_amdgcn_mfma_f32_16x16x32_f16((A), (B), (C), 0, 0, 0)

// One wave owns a 16-row tile end-to-end.  fp16 MFMA, fp32 accum.
// A-frag: row = lane&15, k = 32*s + 8*(lane>>4) + j.  C-layout (m89):
// col = lane&15, row = 4*(lane>>4) + reg.
//
// Base = r10 (96.9us): weight frags in block-shared LDS table (frag-major,
// byte = frag*1024 + lane*16, conflict-free ds_read_b128) -- freed ~72 regs.
// r11 (3 vars at once: (256,5) pin + overlay + stagger) regressed; reverted.
//
// This round: one-tile-ahead prefetch, retried in the r10 register regime
// (r8's failure was 164 weight-hoarded regs + 26 pipeline regs >> 128 cap;
// now 84-100 + ~26 fits).  Current tile's A-frags are packed FIRST (killing
// the xv regs), then next-tile x loads issue (sched_barrier-pinned; also
// cannot sink past the body's "memory"-clobber drains).  Next-tile embed
// gathers issue after layer-2 (~800cyc after their x operands).  Both are
// consumed next iteration -> full-body slack covers the ~1800cyc chain.
__global__ __launch_bounds__(256, 4) void mlp_mfma_kernel(
    const float* __restrict__ x,
    const float* __restrict__ alpha,
    const float* __restrict__ beta,
    const float* __restrict__ gamma,
    const float* __restrict__ gscal,
    const float* __restrict__ W1, const float* __restrict__ b1,
    const float* __restrict__ W2, const float* __restrict__ b2,
    const float* __restrict__ Wres, const float* __restrict__ bres,
    const float* __restrict__ W6, const float* __restrict__ b6,
    float* __restrict__ out, int B)
{
    const int lane = threadIdx.x & 63;
    const int wid  = threadIdx.x >> 6;
    const int c    = lane & 15;   // col (N) index / A-row index
    const int g    = lane >> 4;   // k-group 0..3

    // Weight-fragment table (block-shared): frags 0..11 = W1[t*3+s],
    // 12..15 = W2[12+t*2+s], 16..17 = Wres[16+t].  18 frags x 64 lanes x 16B.
    __shared__ __align__(16) _Float16 wtab[18 * 512];
    // per-wave activation staging (no cross-wave sharing) -- r10 layout
    __shared__ __align__(16) _Float16 h1buf[4][16 * 72];
    __shared__ __align__(16) _Float16 h2buf[4][16 * 40];
    _Float16* __restrict__ h1b = h1buf[wid];
    _Float16* __restrict__ h2b = h2buf[wid];

    // ---- build weight tables once (wave 0) ----
    if (wid == 0) {
        float gm[8];
        #pragma unroll
        for (int j = 0; j < 8; ++j) {
            int k  = 8 * g + j;
            int kc = k < 3 ? 3 : (k > 22 ? 22 : k);     // clamp: safe load
            float gv = gamma[kc];
            gm[j] = (k >= 3 && k < 23) ? gv : 1.0f;
        }
        #pragma unroll
        for (int t = 0; t < 4; ++t)
            #pragma unroll
            for (int s = 0; s < 3; ++s)
                #pragma unroll
                for (int j = 0; j < 8; ++j) {
                    int k  = 32 * s + 8 * g + j;
                    int kc = k < 73 ? k : 72;           // clamp: no OOB load
                    float v = W1[(16 * t + c) * 73 + kc];
                    if (s == 0) v *= gm[j];             // gamma folded into s=0
                    wtab[(t * 3 + s) * 512 + lane * 8 + j] =
                        (k < 73) ? (_Float16)v : (_Float16)0.f;
                }
        #pragma unroll
        for (int t = 0; t < 2; ++t)
            #pragma unroll
            for (int s = 0; s < 2; ++s)
                #pragma unroll
                for (int j = 0; j < 8; ++j)
                    wtab[(12 + t * 2 + s) * 512 + lane * 8 + j] =
                        (_Float16)W2[(16 * t + c) * 64 + 32 * s + 8 * g + j];
        #pragma unroll
        for (int t = 0; t < 2; ++t)
            #pragma unroll
            for (int j = 0; j < 8; ++j)
                wtab[(16 + t) * 512 + lane * 8 + j] =
                    (_Float16)Wres[(16 * t + c) * 32 + 8 * g + j];
    }

    // biases / final weights stay in registers (10 regs)
    float b1f[4], b2f[2], brf[2], w6f[2];
    #pragma unroll
    for (int t = 0; t < 4; ++t) b1f[t] = b1[16 * t + c];
    #pragma unroll
    for (int t = 0; t < 2; ++t) { b2f[t] = b2[16 * t + c]; brf[t] = bres[16 * t + c]; w6f[t] = W6[16 * t + c]; }
    const float b6g = b6[0] + gscal[0];

    __syncthreads();   // table visible to all waves (once, outside hot loop)

    const _Float16* wt = wtab + lane * 8;   // shared vaddr; frag f at +f*512

    const int ntiles = B >> 4;
    const int totw   = gridDim.x * 4;
    int tile = blockIdx.x * 4 + wid;   // always < ntiles (4096 waves << 65536)

    // ---- prologue: first tile's loads + gathers (one cold stall) ----
    float xv0[8], xv1[8], xv2[8];
    float xa = 0.f, xb = 0.f;
    {
        const float* xr = x + (size_t)((tile << 4) + c) * 73;
        #pragma unroll
        for (int j = 0; j < 8; ++j) xv0[j] = xr[8 * g + j];
        #pragma unroll
        for (int j = 0; j < 8; ++j) xv1[j] = xr[32 + 8 * g + j];
        #pragma unroll
        for (int j = 0; j < 8; ++j) {
            int k = 64 + 8 * g + j;
            float v = xr[k < 73 ? k : 72];
            xv2[j] = (k < 73) ? v : 0.f;
        }
        if (g == 0) {
            xa = alpha[(int)xv0[0]];
            xb = beta[(int)xv0[1]];
        }
    }

    for (; tile < ntiles; tile += totw) {
        const int R0  = tile << 4;
        const int nt  = tile + totw;
        const int ntc = (nt < ntiles) ? nt : tile;   // tail: re-read cur (discarded)
        const float* __restrict__ xrn = x + (size_t)((ntc << 4) + c) * 73;

        // ---- pack CUR A-frags (xv/xa/xb landed last iter; frees xv regs) ----
        union H8 { half8 h8; fp16x2 h2[4]; };
        H8 a0u, a1u, a2u;
        #pragma unroll
        for (int j = 0; j < 4; ++j) {
            a0u.h2[j] = __builtin_amdgcn_cvt_pkrtz(xv0[2 * j], xv0[2 * j + 1]);
            a1u.h2[j] = __builtin_amdgcn_cvt_pkrtz(xv1[2 * j], xv1[2 * j + 1]);
            a2u.h2[j] = __builtin_amdgcn_cvt_pkrtz(xv2[2 * j], xv2[2 * j + 1]);
        }
        {
            fp16x2 we = __builtin_amdgcn_cvt_pkrtz(xa, xb);
            if (g == 0) a0u.h2[0] = we;   // embed cols 0/1 on g==0 lanes
        }

        // ---- issue NEXT tile's x loads (xv regs just died; pinned) ----
        float lf0[8], lf1[8], lf2[8];
        #pragma unroll
        for (int j = 0; j < 8; ++j) lf0[j] = xrn[8 * g + j];
        #pragma unroll
        for (int j = 0; j < 8; ++j) lf1[j] = xrn[32 + 8 * g + j];
        #pragma unroll
        for (int j = 0; j < 8; ++j) {
            int k = 64 + 8 * g + j;
            float v = xrn[k < 73 ? k : 72];
            lf2[j] = (k < 73) ? v : 0.f;
        }
        __builtin_amdgcn_sched_barrier(0);   // loads may not sink below this

        // ---- layer 1: 73->64 (weight frags from LDS table) ----
        f32x4 acc[4];
        #pragma unroll
        for (int t = 0; t < 4; ++t) { f32x4 z = { b1f[t], b1f[t], b1f[t], b1f[t] }; acc[t] = z; }
        #pragma unroll
        for (int t = 0; t < 4; ++t)
            acc[t] = MFMA16(a1u.h8, *reinterpret_cast<const half8*>(wt + (t * 3 + 1) * 512), acc[t]);
        #pragma unroll
        for (int t = 0; t < 4; ++t)
            acc[t] = MFMA16(a2u.h8, *reinterpret_cast<const half8*>(wt + (t * 3 + 2) * 512), acc[t]);
        #pragma unroll
        for (int t = 0; t < 4; ++t)
            acc[t] = MFMA16(a0u.h8, *reinterpret_cast<const half8*>(wt + (t * 3 + 0) * 512), acc[t]);

        // GELU -> h1 to LDS (row = 4g+r, col = 16t+c, stride 72)
        #pragma unroll
        for (int t = 0; t < 4; ++t)
            #pragma unroll
            for (int r = 0; r < 4; ++r)
                h1b[(4 * g + r) * 72 + 16 * t + c] = (_Float16)gelu_f(acc[t][r]);

        asm volatile("s_waitcnt lgkmcnt(0)" ::: "memory");

        // ---- layer 2: 64->32 ----
        half8 a2f0 = *reinterpret_cast<const half8*>(&h1b[c * 72 + 8 * g]);
        half8 a2f1 = *reinterpret_cast<const half8*>(&h1b[c * 72 + 32 + 8 * g]);
        f32x4 ac2[2];
        #pragma unroll
        for (int t = 0; t < 2; ++t) {
            f32x4 z = { b2f[t], b2f[t], b2f[t], b2f[t] };
            z = MFMA16(a2f0, *reinterpret_cast<const half8*>(wt + (12 + t * 2) * 512), z);
            ac2[t] = MFMA16(a2f1, *reinterpret_cast<const half8*>(wt + (13 + t * 2) * 512), z);
        }

        // ---- NEXT tile's embed gathers (lf0 landed ~layer-1 ago; pinned) ----
        float nxa = 0.f, nxb = 0.f;
        if (g == 0) {
            nxa = alpha[(int)lf0[0]];
            nxb = beta[(int)lf0[1]];
        }
        __builtin_amdgcn_sched_barrier(0);   // gathers may not sink below this

        float h2c[2][4];
        #pragma unroll
        for (int t = 0; t < 2; ++t)
            #pragma unroll
            for (int r = 0; r < 4; ++r)
                h2c[t][r] = gelu_f(ac2[t][r]);

        // h2 to LDS (stride 40)
        #pragma unroll
        for (int t = 0; t < 2; ++t)
            #pragma unroll
            for (int r = 0; r < 4; ++r)
                h2b[(4 * g + r) * 40 + 16 * t + c] = (_Float16)h2c[t][r];

        asm volatile("s_waitcnt lgkmcnt(0)" ::: "memory");

        // ---- residual layer: C-init = bres + h2 (matching C-layout slots) ----
        half8 arf = *reinterpret_cast<const half8*>(&h2b[c * 40 + 8 * g]);
        f32x4 acr[2];
        #pragma unroll
        for (int t = 0; t < 2; ++t) {
            f32x4 z = { brf[t] + h2c[t][0], brf[t] + h2c[t][1],
                        brf[t] + h2c[t][2], brf[t] + h2c[t][3] };
            acr[t] = MFMA16(arf, *reinterpret_cast<const half8*>(wt + (16 + t) * 512), z);
        }

        // ---- final 32->1: per-lane partial, butterfly-reduce over c ----
        f32x4 p;
        #pragma unroll
        for (int r = 0; r < 4; ++r)
            p[r] = gelu_f(acr[0][r]) * w6f[0] + gelu_f(acr[1][r]) * w6f[1];
        #pragma unroll
        for (int m = 1; m < 16; m <<= 1) {
            #pragma unroll
            for (int r = 0; r < 4; ++r) p[r] += __shfl_xor(p[r], m, 64);
        }
        if (c == 0) {
            f32x4 o = { p[0] + b6g, p[1] + b6g, p[2] + b6g, p[3] + b6g };
            *reinterpret_cast<f32x4*>(out + R0 + 4 * g) = o;  // rows R0+4g..+3
        }

        // ---- rotate pipeline state (static indices; coalesces to renames) ----
        #pragma unroll
        for (int j = 0; j < 8; ++j) { xv0[j] = lf0[j]; xv1[j] = lf1[j]; xv2[j] = lf2[j]; }
        xa = nxa; xb = nxb;
    }
}

extern "C" void kernel_launch(void* const* d_in, const int* in_sizes, int n_in,
                              void* d_out, int out_size, void* d_ws, size_t ws_size,
                              hipStream_t stream) {
    const float* x     = (const float*)d_in[0];
    const float* alpha = (const float*)d_in[1];
    const float* beta  = (const float*)d_in[2];
    const float* gamma = (const float*)d_in[3];
    const float* g     = (const float*)d_in[4];
    const float* W1    = (const float*)d_in[5];
    const float* b1    = (const float*)d_in[6];
    const float* W2    = (const float*)d_in[7];
    const float* b2    = (const float*)d_in[8];
    const float* Wres  = (const float*)d_in[9];
    const float* bres  = (const float*)d_in[10];
    const float* W6    = (const float*)d_in[11];
    const float* b6    = (const float*)d_in[12];
    float* out = (float*)d_out;

    int B = out_size;          // 1e6 rows; divisible by 16
    // 1024 blocks = exactly 4 blocks/CU resident (LDS 32KB x 4 = 128KB,
    // 16 waves/CU at the 128-VGPR tier) -- r10's proven residency.
    int nblocks = 1024;
    mlp_mfma_kernel<<<nblocks, 256, 0, stream>>>(x, alpha, beta, gamma, g,
                                                 W1, b1, W2, b2, Wres, bres,
                                                 W6, b6, out, B);
}

// Round 13
// 100.926 us; speedup vs baseline: 2.0121x; 2.0121x over previous
//
#include <hip/hip_runtime.h>
#include <math.h>

typedef _Float16 half8 __attribute__((ext_vector_type(8)));
typedef __fp16   fp16x2 __attribute__((ext_vector_type(2)));  // cvt_pkrtz's return type
typedef float f32x4 __attribute__((ext_vector_type(4)));

// Branchless exact-grade GELU: x*0.5*(1+erf(x/sqrt(2))) with A&S 7.1.26 erf,
// |erf err| <= 1.5e-7 (vs output threshold 2.47e-2).
__device__ __forceinline__ float gelu_f(float v) {
    float y  = v * 0.70710678118654752f;
    float ay = __builtin_fabsf(y);
    float t  = __builtin_amdgcn_rcpf(__builtin_fmaf(0.3275911f, ay, 1.0f));
    float p  = __builtin_fmaf(t, 1.061405429f, -1.453152027f);
    p = __builtin_fmaf(p, t, 1.421413741f);
    p = __builtin_fmaf(p, t, -0.284496736f);
    p = __builtin_fmaf(p, t, 0.254829592f);
    p = p * t;
    float e  = __builtin_amdgcn_exp2f(ay * ay * -1.4426950408889634f);
    float er = __builtin_fmaf(-p, e, 1.0f);        // erf(|y|), saturates to 1
    er = __builtin_copysignf(er, v);               // restore sign
    float hv = 0.5f * v;
    return __builtin_fmaf(hv, er, hv);
}

#define MFMA16(A, B, C) __builtin_amdgcn_mfma_f32_16x16x32_f16((A), (B), (C), 0, 0, 0)

// One wave owns a 16-row tile end-to-end.  fp16 MFMA, fp32 accum.
// A-frag: row = lane&15, k = 32*s + 8*(lane>>4) + j.  C-layout (m89):
// col = lane&15, row = 4*(lane>>4) + reg.
//
// Base = r10 (96.9us): weight frags in block-shared LDS table (frag-major,
// byte = frag*1024 + lane*16, conflict-free ds_read_b128) -- freed ~72 regs.
// Pipelining is 0-for-3 (r7 sunk / r8 spilled / r12 order-pin-serialized,
// the m141 pattern) -- permanently abandoned.
//
// This round, ONE variable vs r10: grid 1024 -> 1280.  r10's own counters
// show the 5th block/CU fits: VGPR 84 -> floor(512/84)=6 waves/SIMD from
// registers; LDS 32768 x 5 = 163840 B = exactly 160 KiB.  Grid was the only
// limiter.
__global__ __launch_bounds__(256, 4) void mlp_mfma_kernel(
    const float* __restrict__ x,
    const float* __restrict__ alpha,
    const float* __restrict__ beta,
    const float* __restrict__ gamma,
    const float* __restrict__ gscal,
    const float* __restrict__ W1, const float* __restrict__ b1,
    const float* __restrict__ W2, const float* __restrict__ b2,
    const float* __restrict__ Wres, const float* __restrict__ bres,
    const float* __restrict__ W6, const float* __restrict__ b6,
    float* __restrict__ out, int B)
{
    const int lane = threadIdx.x & 63;
    const int wid  = threadIdx.x >> 6;
    const int c    = lane & 15;   // col (N) index / A-row index
    const int g    = lane >> 4;   // k-group 0..3

    // Weight-fragment table (block-shared): frags 0..11 = W1[t*3+s],
    // 12..15 = W2[12+t*2+s], 16..17 = Wres[16+t].  18 frags x 64 lanes x 16B.
    __shared__ __align__(16) _Float16 wtab[18 * 512];
    // per-wave activation staging (no cross-wave sharing)
    __shared__ __align__(16) _Float16 h1buf[4][16 * 72]; // stride 72 (16B-aligned rows)
    __shared__ __align__(16) _Float16 h2buf[4][16 * 40];
    _Float16* __restrict__ h1b = h1buf[wid];
    _Float16* __restrict__ h2b = h2buf[wid];

    // ---- build weight tables once (wave 0) ----
    if (wid == 0) {
        // gamma multipliers for k-step 0 (k = 8g+j; scale cols 3..22 only)
        float gm[8];
        #pragma unroll
        for (int j = 0; j < 8; ++j) {
            int k  = 8 * g + j;
            int kc = k < 3 ? 3 : (k > 22 ? 22 : k);     // clamp: safe load
            float gv = gamma[kc];
            gm[j] = (k >= 3 && k < 23) ? gv : 1.0f;
        }
        // W1: [64,73], frag b[j] = W1[16t+c][32s+8g+j], gamma folded into s=0,
        // zero-pad k>=73
        #pragma unroll
        for (int t = 0; t < 4; ++t)
            #pragma unroll
            for (int s = 0; s < 3; ++s)
                #pragma unroll
                for (int j = 0; j < 8; ++j) {
                    int k  = 32 * s + 8 * g + j;
                    int kc = k < 73 ? k : 72;           // clamp: no OOB load
                    float v = W1[(16 * t + c) * 73 + kc];
                    if (s == 0) v *= gm[j];
                    wtab[(t * 3 + s) * 512 + lane * 8 + j] =
                        (k < 73) ? (_Float16)v : (_Float16)0.f;
                }
        // W2: [32,64]
        #pragma unroll
        for (int t = 0; t < 2; ++t)
            #pragma unroll
            for (int s = 0; s < 2; ++s)
                #pragma unroll
                for (int j = 0; j < 8; ++j)
                    wtab[(12 + t * 2 + s) * 512 + lane * 8 + j] =
                        (_Float16)W2[(16 * t + c) * 64 + 32 * s + 8 * g + j];
        // Wres: [32,32]
        #pragma unroll
        for (int t = 0; t < 2; ++t)
            #pragma unroll
            for (int j = 0; j < 8; ++j)
                wtab[(16 + t) * 512 + lane * 8 + j] =
                    (_Float16)Wres[(16 * t + c) * 32 + 8 * g + j];
    }

    // biases / final weights stay in registers (10 regs)
    float b1f[4], b2f[2], brf[2], w6f[2];
    #pragma unroll
    for (int t = 0; t < 4; ++t) b1f[t] = b1[16 * t + c];
    #pragma unroll
    for (int t = 0; t < 2; ++t) { b2f[t] = b2[16 * t + c]; brf[t] = bres[16 * t + c]; w6f[t] = W6[16 * t + c]; }
    const float b6g = b6[0] + gscal[0];

    __syncthreads();   // table visible to all waves (once, outside hot loop)

    const _Float16* wt = wtab + lane * 8;   // shared vaddr; frag f at +f*512

    const int ntiles = B >> 4;
    const int totw   = gridDim.x * 4;
    for (int tile = blockIdx.x * 4 + wid; tile < ntiles; tile += totw) {
        const int R0 = tile << 4;
        const float* __restrict__ xr = x + (size_t)(R0 + c) * 73;

        // ---- x loads (issued up front) ----
        float xv0[8], xv1[8], xv2[8];
        #pragma unroll
        for (int j = 0; j < 8; ++j) xv0[j] = xr[8 * g + j];
        #pragma unroll
        for (int j = 0; j < 8; ++j) xv1[j] = xr[32 + 8 * g + j];
        #pragma unroll
        for (int j = 0; j < 8; ++j) {
            int k = 64 + 8 * g + j;
            float v = xr[k < 73 ? k : 72];
            xv2[j] = (k < 73) ? v : 0.f;
        }

        // embed gathers (only g==0 lanes own cols 0/1); consumed by the LAST
        // k-step's MFMAs
        float xa = 0.f, xb = 0.f;
        if (g == 0) {
            xa = alpha[(int)xv0[0]];
            xb = beta[(int)xv0[1]];
        }

        // ---- W1 frags from LDS (re-read each tile; drains block LICM) ----
        half8 w1f[4][3];
        #pragma unroll
        for (int t = 0; t < 4; ++t)
            #pragma unroll
            for (int s = 0; s < 3; ++s)
                w1f[t][s] = *reinterpret_cast<const half8*>(wt + (t * 3 + s) * 512);

        // ---- layer 1: 73->64.  k-steps 1,2 first (no gather dep) ----
        union H8 { half8 h8; fp16x2 h2[4]; };
        H8 a1u, a2u;
        #pragma unroll
        for (int j = 0; j < 4; ++j) {
            a1u.h2[j] = __builtin_amdgcn_cvt_pkrtz(xv1[2 * j], xv1[2 * j + 1]);
            a2u.h2[j] = __builtin_amdgcn_cvt_pkrtz(xv2[2 * j], xv2[2 * j + 1]);
        }
        f32x4 acc[4];
        #pragma unroll
        for (int t = 0; t < 4; ++t) { f32x4 z = { b1f[t], b1f[t], b1f[t], b1f[t] }; acc[t] = z; }
        #pragma unroll
        for (int t = 0; t < 4; ++t) acc[t] = MFMA16(a1u.h8, w1f[t][1], acc[t]);
        #pragma unroll
        for (int t = 0; t < 4; ++t) acc[t] = MFMA16(a2u.h8, w1f[t][2], acc[t]);

        // k-step 0 last: gamma pre-folded; cols 0/1 replaced by embeds
        H8 a0u;
        #pragma unroll
        for (int j = 0; j < 4; ++j)
            a0u.h2[j] = __builtin_amdgcn_cvt_pkrtz(xv0[2 * j], xv0[2 * j + 1]);
        {
            fp16x2 we = __builtin_amdgcn_cvt_pkrtz(xa, xb);
            if (g == 0) a0u.h2[0] = we;
        }
        #pragma unroll
        for (int t = 0; t < 4; ++t) acc[t] = MFMA16(a0u.h8, w1f[t][0], acc[t]);

        // GELU -> h1 to LDS (row = 4g+r, col = 16t+c, stride 72)
        #pragma unroll
        for (int t = 0; t < 4; ++t)
            #pragma unroll
            for (int r = 0; r < 4; ++r)
                h1b[(4 * g + r) * 72 + 16 * t + c] = (_Float16)gelu_f(acc[t][r]);

        asm volatile("s_waitcnt lgkmcnt(0)" ::: "memory");

        // ---- layer 2: 64->32 ----
        half8 w2f[2][2];
        #pragma unroll
        for (int t = 0; t < 2; ++t)
            #pragma unroll
            for (int s = 0; s < 2; ++s)
                w2f[t][s] = *reinterpret_cast<const half8*>(wt + (12 + t * 2 + s) * 512);

        half8 a2f0 = *reinterpret_cast<const half8*>(&h1b[c * 72 + 8 * g]);
        half8 a2f1 = *reinterpret_cast<const half8*>(&h1b[c * 72 + 32 + 8 * g]);
        f32x4 ac2[2];
        #pragma unroll
        for (int t = 0; t < 2; ++t) {
            f32x4 z = { b2f[t], b2f[t], b2f[t], b2f[t] };
            z = MFMA16(a2f0, w2f[t][0], z);
            ac2[t] = MFMA16(a2f1, w2f[t][1], z);
        }
        float h2c[2][4];
        #pragma unroll
        for (int t = 0; t < 2; ++t)
            #pragma unroll
            for (int r = 0; r < 4; ++r)
                h2c[t][r] = gelu_f(ac2[t][r]);

        // h2 to LDS (stride 40)
        #pragma unroll
        for (int t = 0; t < 2; ++t)
            #pragma unroll
            for (int r = 0; r < 4; ++r)
                h2b[(4 * g + r) * 40 + 16 * t + c] = (_Float16)h2c[t][r];

        asm volatile("s_waitcnt lgkmcnt(0)" ::: "memory");

        // ---- residual layer: C-init = bres + h2 (matching C-layout slots) ----
        half8 wrf[2];
        #pragma unroll
        for (int t = 0; t < 2; ++t)
            wrf[t] = *reinterpret_cast<const half8*>(wt + (16 + t) * 512);

        half8 arf = *reinterpret_cast<const half8*>(&h2b[c * 40 + 8 * g]);
        f32x4 acr[2];
        #pragma unroll
        for (int t = 0; t < 2; ++t) {
            f32x4 z = { brf[t] + h2c[t][0], brf[t] + h2c[t][1],
                        brf[t] + h2c[t][2], brf[t] + h2c[t][3] };
            acr[t] = MFMA16(arf, wrf[t], z);
        }

        // ---- final 32->1: per-lane partial, butterfly-reduce over c ----
        f32x4 p;
        #pragma unroll
        for (int r = 0; r < 4; ++r)
            p[r] = gelu_f(acr[0][r]) * w6f[0] + gelu_f(acr[1][r]) * w6f[1];
        #pragma unroll
        for (int m = 1; m < 16; m <<= 1) {
            #pragma unroll
            for (int r = 0; r < 4; ++r) p[r] += __shfl_xor(p[r], m, 64);
        }
        if (c == 0) {
            f32x4 o = { p[0] + b6g, p[1] + b6g, p[2] + b6g, p[3] + b6g };
            *reinterpret_cast<f32x4*>(out + R0 + 4 * g) = o;  // rows R0+4g..+3
        }
    }
}

extern "C" void kernel_launch(void* const* d_in, const int* in_sizes, int n_in,
                              void* d_out, int out_size, void* d_ws, size_t ws_size,
                              hipStream_t stream) {
    const float* x     = (const float*)d_in[0];
    const float* alpha = (const float*)d_in[1];
    const float* beta  = (const float*)d_in[2];
    const float* gamma = (const float*)d_in[3];
    const float* g     = (const float*)d_in[4];
    const float* W1    = (const float*)d_in[5];
    const float* b1    = (const float*)d_in[6];
    const float* W2    = (const float*)d_in[7];
    const float* b2    = (const float*)d_in[8];
    const float* Wres  = (const float*)d_in[9];
    const float* bres  = (const float*)d_in[10];
    const float* W6    = (const float*)d_in[11];
    const float* b6    = (const float*)d_in[12];
    float* out = (float*)d_out;

    int B = out_size;          // 1e6 rows; divisible by 16
    // 1280 blocks = 5 blocks/CU: LDS 32768 x 5 = 163840 B (exactly 160 KiB),
    // VGPR 84 -> 6 waves/SIMD register headroom.  ONE variable vs r10.
    int nblocks = 1280;
    mlp_mfma_kernel<<<nblocks, 256, 0, stream>>>(x, alpha, beta, gamma, g,
                                                 W1, b1, W2, b2, Wres, bres,
                                                 W6, b6, out, B);
}

// Round 14
// 96.768 us; speedup vs baseline: 2.0986x; 1.0430x over previous
//
#include <hip/hip_runtime.h>
#include <math.h>

typedef _Float16 half8 __attribute__((ext_vector_type(8)));
typedef __fp16   fp16x2 __attribute__((ext_vector_type(2)));  // cvt_pkrtz's return type
typedef float f32x4 __attribute__((ext_vector_type(4)));

// Branchless exact-grade GELU: x*0.5*(1+erf(x/sqrt(2))) with A&S 7.1.26 erf,
// |erf err| <= 1.5e-7 (vs output threshold 2.47e-2).
__device__ __forceinline__ float gelu_f(float v) {
    float y  = v * 0.70710678118654752f;
    float ay = __builtin_fabsf(y);
    float t  = __builtin_amdgcn_rcpf(__builtin_fmaf(0.3275911f, ay, 1.0f));
    float p  = __builtin_fmaf(t, 1.061405429f, -1.453152027f);
    p = __builtin_fmaf(p, t, 1.421413741f);
    p = __builtin_fmaf(p, t, -0.284496736f);
    p = __builtin_fmaf(p, t, 0.254829592f);
    p = p * t;
    float e  = __builtin_amdgcn_exp2f(ay * ay * -1.4426950408889634f);
    float er = __builtin_fmaf(-p, e, 1.0f);        // erf(|y|), saturates to 1
    er = __builtin_copysignf(er, v);               // restore sign
    float hv = 0.5f * v;
    return __builtin_fmaf(hv, er, hv);
}

#define MFMA16(A, B, C) __builtin_amdgcn_mfma_f32_16x16x32_f16((A), (B), (C), 0, 0, 0)

// One wave owns a 16-row tile end-to-end.  fp16 MFMA, fp32 accum.
// A-frag: row = lane&15, k = 32*s + 8*(lane>>4) + j.  C-layout (m89):
// col = lane&15, row = 4*(lane>>4) + reg.
//
// Base = r10 (96.9us).  r13 showed 5 blocks/CU at 4-wave blocks doesn't fit
// (LDS exactly 160KiB -> ragged scheduling).  The real residency ceiling was
// the per-block 18KB wtab duplicated per block: 4-wave blocks cap at 16
// waves/CU = 4 waves/SIMD while VGPR=84 permits 6.
//
// This round, ONE structural variable: 8-wave (512-thread) blocks.  One wtab
// amortized over 8 waves -> LDS/block = 18432 + 8*(2304+1280) = 47104 B ->
// 3 blocks/CU (141KB) * 8 waves = 24 waves/CU = 6 waves/SIMD = the VGPR
// ceiling (6*84=504<=512).  Loop body identical to r10.
__global__ __launch_bounds__(512, 4) void mlp_mfma_kernel(
    const float* __restrict__ x,
    const float* __restrict__ alpha,
    const float* __restrict__ beta,
    const float* __restrict__ gamma,
    const float* __restrict__ gscal,
    const float* __restrict__ W1, const float* __restrict__ b1,
    const float* __restrict__ W2, const float* __restrict__ b2,
    const float* __restrict__ Wres, const float* __restrict__ bres,
    const float* __restrict__ W6, const float* __restrict__ b6,
    float* __restrict__ out, int B)
{
    const int lane = threadIdx.x & 63;
    const int wid  = threadIdx.x >> 6;   // 0..7
    const int c    = lane & 15;   // col (N) index / A-row index
    const int g    = lane >> 4;   // k-group 0..3

    // Weight-fragment table (block-shared): frags 0..11 = W1[t*3+s],
    // 12..15 = W2[12+t*2+s], 16..17 = Wres[16+t].  18 frags x 64 lanes x 16B.
    __shared__ __align__(16) _Float16 wtab[18 * 512];
    // per-wave activation staging (no cross-wave sharing)
    __shared__ __align__(16) _Float16 h1buf[8][16 * 72]; // stride 72 (16B-aligned rows)
    __shared__ __align__(16) _Float16 h2buf[8][16 * 40];
    _Float16* __restrict__ h1b = h1buf[wid];
    _Float16* __restrict__ h2b = h2buf[wid];

    // ---- build weight tables once (wave 0) ----
    if (wid == 0) {
        // gamma multipliers for k-step 0 (k = 8g+j; scale cols 3..22 only)
        float gm[8];
        #pragma unroll
        for (int j = 0; j < 8; ++j) {
            int k  = 8 * g + j;
            int kc = k < 3 ? 3 : (k > 22 ? 22 : k);     // clamp: safe load
            float gv = gamma[kc];
            gm[j] = (k >= 3 && k < 23) ? gv : 1.0f;
        }
        // W1: [64,73], frag b[j] = W1[16t+c][32s+8g+j], gamma folded into s=0,
        // zero-pad k>=73
        #pragma unroll
        for (int t = 0; t < 4; ++t)
            #pragma unroll
            for (int s = 0; s < 3; ++s)
                #pragma unroll
                for (int j = 0; j < 8; ++j) {
                    int k  = 32 * s + 8 * g + j;
                    int kc = k < 73 ? k : 72;           // clamp: no OOB load
                    float v = W1[(16 * t + c) * 73 + kc];
                    if (s == 0) v *= gm[j];
                    wtab[(t * 3 + s) * 512 + lane * 8 + j] =
                        (k < 73) ? (_Float16)v : (_Float16)0.f;
                }
        // W2: [32,64]
        #pragma unroll
        for (int t = 0; t < 2; ++t)
            #pragma unroll
            for (int s = 0; s < 2; ++s)
                #pragma unroll
                for (int j = 0; j < 8; ++j)
                    wtab[(12 + t * 2 + s) * 512 + lane * 8 + j] =
                        (_Float16)W2[(16 * t + c) * 64 + 32 * s + 8 * g + j];
        // Wres: [32,32]
        #pragma unroll
        for (int t = 0; t < 2; ++t)
            #pragma unroll
            for (int j = 0; j < 8; ++j)
                wtab[(16 + t) * 512 + lane * 8 + j] =
                    (_Float16)Wres[(16 * t + c) * 32 + 8 * g + j];
    }

    // biases / final weights stay in registers (10 regs)
    float b1f[4], b2f[2], brf[2], w6f[2];
    #pragma unroll
    for (int t = 0; t < 4; ++t) b1f[t] = b1[16 * t + c];
    #pragma unroll
    for (int t = 0; t < 2; ++t) { b2f[t] = b2[16 * t + c]; brf[t] = bres[16 * t + c]; w6f[t] = W6[16 * t + c]; }
    const float b6g = b6[0] + gscal[0];

    __syncthreads();   // table visible to all waves (once, outside hot loop)

    const _Float16* wt = wtab + lane * 8;   // shared vaddr; frag f at +f*512

    const int ntiles = B >> 4;
    const int totw   = gridDim.x * 8;
    for (int tile = blockIdx.x * 8 + wid; tile < ntiles; tile += totw) {
        const int R0 = tile << 4;
        const float* __restrict__ xr = x + (size_t)(R0 + c) * 73;

        // ---- x loads (issued up front) ----
        float xv0[8], xv1[8], xv2[8];
        #pragma unroll
        for (int j = 0; j < 8; ++j) xv0[j] = xr[8 * g + j];
        #pragma unroll
        for (int j = 0; j < 8; ++j) xv1[j] = xr[32 + 8 * g + j];
        #pragma unroll
        for (int j = 0; j < 8; ++j) {
            int k = 64 + 8 * g + j;
            float v = xr[k < 73 ? k : 72];
            xv2[j] = (k < 73) ? v : 0.f;
        }

        // embed gathers (only g==0 lanes own cols 0/1); consumed by the LAST
        // k-step's MFMAs
        float xa = 0.f, xb = 0.f;
        if (g == 0) {
            xa = alpha[(int)xv0[0]];
            xb = beta[(int)xv0[1]];
        }

        // ---- W1 frags from LDS (re-read each tile; drains block LICM) ----
        half8 w1f[4][3];
        #pragma unroll
        for (int t = 0; t < 4; ++t)
            #pragma unroll
            for (int s = 0; s < 3; ++s)
                w1f[t][s] = *reinterpret_cast<const half8*>(wt + (t * 3 + s) * 512);

        // ---- layer 1: 73->64.  k-steps 1,2 first (no gather dep) ----
        union H8 { half8 h8; fp16x2 h2[4]; };
        H8 a1u, a2u;
        #pragma unroll
        for (int j = 0; j < 4; ++j) {
            a1u.h2[j] = __builtin_amdgcn_cvt_pkrtz(xv1[2 * j], xv1[2 * j + 1]);
            a2u.h2[j] = __builtin_amdgcn_cvt_pkrtz(xv2[2 * j], xv2[2 * j + 1]);
        }
        f32x4 acc[4];
        #pragma unroll
        for (int t = 0; t < 4; ++t) { f32x4 z = { b1f[t], b1f[t], b1f[t], b1f[t] }; acc[t] = z; }
        #pragma unroll
        for (int t = 0; t < 4; ++t) acc[t] = MFMA16(a1u.h8, w1f[t][1], acc[t]);
        #pragma unroll
        for (int t = 0; t < 4; ++t) acc[t] = MFMA16(a2u.h8, w1f[t][2], acc[t]);

        // k-step 0 last: gamma pre-folded; cols 0/1 replaced by embeds
        H8 a0u;
        #pragma unroll
        for (int j = 0; j < 4; ++j)
            a0u.h2[j] = __builtin_amdgcn_cvt_pkrtz(xv0[2 * j], xv0[2 * j + 1]);
        {
            fp16x2 we = __builtin_amdgcn_cvt_pkrtz(xa, xb);
            if (g == 0) a0u.h2[0] = we;
        }
        #pragma unroll
        for (int t = 0; t < 4; ++t) acc[t] = MFMA16(a0u.h8, w1f[t][0], acc[t]);

        // GELU -> h1 to LDS (row = 4g+r, col = 16t+c, stride 72)
        #pragma unroll
        for (int t = 0; t < 4; ++t)
            #pragma unroll
            for (int r = 0; r < 4; ++r)
                h1b[(4 * g + r) * 72 + 16 * t + c] = (_Float16)gelu_f(acc[t][r]);

        asm volatile("s_waitcnt lgkmcnt(0)" ::: "memory");

        // ---- layer 2: 64->32 ----
        half8 w2f[2][2];
        #pragma unroll
        for (int t = 0; t < 2; ++t)
            #pragma unroll
            for (int s = 0; s < 2; ++s)
                w2f[t][s] = *reinterpret_cast<const half8*>(wt + (12 + t * 2 + s) * 512);

        half8 a2f0 = *reinterpret_cast<const half8*>(&h1b[c * 72 + 8 * g]);
        half8 a2f1 = *reinterpret_cast<const half8*>(&h1b[c * 72 + 32 + 8 * g]);
        f32x4 ac2[2];
        #pragma unroll
        for (int t = 0; t < 2; ++t) {
            f32x4 z = { b2f[t], b2f[t], b2f[t], b2f[t] };
            z = MFMA16(a2f0, w2f[t][0], z);
            ac2[t] = MFMA16(a2f1, w2f[t][1], z);
        }
        float h2c[2][4];
        #pragma unroll
        for (int t = 0; t < 2; ++t)
            #pragma unroll
            for (int r = 0; r < 4; ++r)
                h2c[t][r] = gelu_f(ac2[t][r]);

        // h2 to LDS (stride 40)
        #pragma unroll
        for (int t = 0; t < 2; ++t)
            #pragma unroll
            for (int r = 0; r < 4; ++r)
                h2b[(4 * g + r) * 40 + 16 * t + c] = (_Float16)h2c[t][r];

        asm volatile("s_waitcnt lgkmcnt(0)" ::: "memory");

        // ---- residual layer: C-init = bres + h2 (matching C-layout slots) ----
        half8 wrf[2];
        #pragma unroll
        for (int t = 0; t < 2; ++t)
            wrf[t] = *reinterpret_cast<const half8*>(wt + (16 + t) * 512);

        half8 arf = *reinterpret_cast<const half8*>(&h2b[c * 40 + 8 * g]);
        f32x4 acr[2];
        #pragma unroll
        for (int t = 0; t < 2; ++t) {
            f32x4 z = { brf[t] + h2c[t][0], brf[t] + h2c[t][1],
                        brf[t] + h2c[t][2], brf[t] + h2c[t][3] };
            acr[t] = MFMA16(arf, wrf[t], z);
        }

        // ---- final 32->1: per-lane partial, butterfly-reduce over c ----
        f32x4 p;
        #pragma unroll
        for (int r = 0; r < 4; ++r)
            p[r] = gelu_f(acr[0][r]) * w6f[0] + gelu_f(acr[1][r]) * w6f[1];
        #pragma unroll
        for (int m = 1; m < 16; m <<= 1) {
            #pragma unroll
            for (int r = 0; r < 4; ++r) p[r] += __shfl_xor(p[r], m, 64);
        }
        if (c == 0) {
            f32x4 o = { p[0] + b6g, p[1] + b6g, p[2] + b6g, p[3] + b6g };
            *reinterpret_cast<f32x4*>(out + R0 + 4 * g) = o;  // rows R0+4g..+3
        }
    }
}

extern "C" void kernel_launch(void* const* d_in, const int* in_sizes, int n_in,
                              void* d_out, int out_size, void* d_ws, size_t ws_size,
                              hipStream_t stream) {
    const float* x     = (const float*)d_in[0];
    const float* alpha = (const float*)d_in[1];
    const float* beta  = (const float*)d_in[2];
    const float* gamma = (const float*)d_in[3];
    const float* g     = (const float*)d_in[4];
    const float* W1    = (const float*)d_in[5];
    const float* b1    = (const float*)d_in[6];
    const float* W2    = (const float*)d_in[7];
    const float* b2    = (const float*)d_in[8];
    const float* Wres  = (const float*)d_in[9];
    const float* bres  = (const float*)d_in[10];
    const float* W6    = (const float*)d_in[11];
    const float* b6    = (const float*)d_in[12];
    float* out = (float*)d_out;

    int B = out_size;          // 1e6 rows; divisible by 16
    // 768 blocks x 512 threads: 3 blocks/CU (LDS 47104 x 3 = 141KB), 8 waves
    // each -> 24 waves/CU = 6 waves/SIMD = the VGPR-84 residency ceiling.
    int nblocks = 768;
    mlp_mfma_kernel<<<nblocks, 512, 0, stream>>>(x, alpha, beta, gamma, g,
                                                 W1, b1, W2, b2, Wres, bres,
                                                 W6, b6, out, B);
}